// Round 16
// baseline (242.620 us; speedup 1.0000x reference)
//
#include <hip/hip_runtime.h>
#include <hip/hip_bf16.h>
#include <math.h>
#include <type_traits>

#define Bn 128
#define Sn 4096
#define Dn 32
#define Hn 192
#define ASTR 196           // LDS act stride (bf16): proven 0-conflict R5-R15
#define CH 32              // recurrence chunks per chain
#define CHL 128            // steps per chunk
#define BURN 128           // burn-in steps
#define HALF_LOG2PI 0.9189385332046727f

typedef __attribute__((ext_vector_type(8))) short short8v;
typedef __attribute__((ext_vector_type(4))) float f32x4;

__device__ __forceinline__ unsigned short f2bf(float x) {
    return (unsigned short)((__float_as_uint(x) + 0x8000u) >> 16);
}
__device__ __forceinline__ unsigned pack_bf2(float lo, float hi) {
    __hip_bfloat162 h = __float22bfloat162_rn(float2{lo, hi});   // v_cvt_pk_bf16_f32
    return *reinterpret_cast<unsigned*>(&h);
}

// ---------------------------------------------------------------------------
// Pack W1/W2/W3 (fp32 [K][192]) into bf16 MFMA fragment order (proven R2-R15):
// fid = layerbase + kstep*12 + nb; lane elem j: W[k0+8*(lane>>4)+j][nb*16+(lane&15)].
// Used as the A operand (free index = output feature).
// ---------------------------------------------------------------------------
__global__ __launch_bounds__(64) void pack_weights(
    const float* __restrict__ W1, const float* __restrict__ W2,
    const float* __restrict__ W3, unsigned short* __restrict__ wp)
{
    int fid = blockIdx.x, lane = threadIdx.x;
    const float* Wsrc; int Krows, f;
    if (fid < 24)      { Wsrc = W1; Krows = 33;  f = fid; }
    else if (fid < 96) { Wsrc = W2; Krows = 192; f = fid - 24; }
    else               { Wsrc = W3; Krows = 192; f = fid - 96; }
    int kstep = f / 12, nb = f % 12;
    int k0 = kstep * 32 + 8 * (lane >> 4);
    int n  = nb * 16 + (lane & 15);
    short8v v;
#pragma unroll
    for (int j = 0; j < 8; ++j) {
        int k = k0 + j;
        float x = (k < Krows) ? Wsrc[k * Hn + n] : 0.0f;
        v[j] = (short)f2bf(x);
    }
    *(short8v*)(wp + (size_t)fid * 512 + lane * 8) = v;
}

// ---------------------------------------------------------------------------
// Recurrence, chunked (contractive burn-in). Unchanged (proven).
// ---------------------------------------------------------------------------
__global__ __launch_bounds__(256) void recurrence_kernel(
    const float* __restrict__ it_g, const float* __restrict__ W,
    const float* __restrict__ v,    const float* __restrict__ bia,
    const float* __restrict__ cinit, unsigned short* __restrict__ ctx)
{
    const float LOG2E = 1.4426950408889634f;
    int g = blockIdx.x * 256 + threadIdx.x;
    int d = g & 31;
    int bc = g >> 5;
    int b = bc & (Bn - 1);
    int chunk = bc >> 7;

    float w0 = W[d], w3 = W[96 + d];
    float nw1l = -W[32 + d] * LOG2E, nw2l = -W[64 + d] * LOG2E;
    float nvfl = -v[d] * LOG2E,      nvrl = -v[32 + d] * LOG2E;
    float nbfl = -bia[d] * LOG2E,    nbrl = -bia[32 + d] * LOG2E;

    const f32x4* itv = (const f32x4*)(it_g + (size_t)b * Sn);
    unsigned short* cp = ctx + ((size_t)b * Sn) * Dn + d;
    int s_start = chunk * CHL;
    int s_end   = s_start + CHL;
    int sbeg    = (chunk == 0) ? 0 : s_start - BURN;
    if (chunk == 0) cp[0] = f2bf(cinit[d]);

    float c = 0.0f;
    int blk0 = sbeg >> 3, blkN = s_end >> 3;
    f32x4 A0 = itv[blk0 * 2], A1 = itv[blk0 * 2 + 1];
    for (int blk = blk0; blk < blkN; ++blk) {
        f32x4 N0 = A0, N1 = A1;
        if (blk + 1 < blkN) { N0 = itv[blk * 2 + 2]; N1 = itv[blk * 2 + 3]; }
        float feat[8];
#pragma unroll
        for (int j = 0; j < 4; ++j) {
            feat[j]     = __logf(A0[j] + 1e-8f);
            feat[j + 4] = __logf(A1[j] + 1e-8f);
        }
        unsigned short hb[8];
#pragma unroll
        for (int j = 0; j < 8; ++j) {
            float ft = feat[j];
            float u0 = ft * w0, u3 = ft * w3;
            float nxfl = fmaf(ft, nw1l, nbfl);
            float nxrl = fmaf(ft, nw2l, nbrl);
            float sfn = fmaf(nvfl, c, nxfl);
            float ef  = __builtin_amdgcn_exp2f(sfn);
            float f_  = __builtin_amdgcn_rcpf(1.0f + ef);
            float cmu = c - u0;
            float cn  = fmaf(f_, cmu, u0);
            float srn = fmaf(nvrl, cn, nxrl);
            float er  = __builtin_amdgcn_exp2f(srn);
            float r_  = __builtin_amdgcn_rcpf(1.0f + er);
            float h   = fmaf(r_, cn - u3, u3);
            c = cn;
            hb[j] = f2bf(h);
        }
        int s0 = blk * 8;
        if (s0 >= s_start) {
#pragma unroll
            for (int j = 0; j < 8; ++j)
                if (s0 + j + 1 < Sn) cp[(size_t)(s0 + j + 1) * Dn] = hb[j];
        }
        A0 = N0; A1 = N1;
    }
}

// ---------------------------------------------------------------------------
// MLP: R15 (2 waves x interleaved 6 n-blocks x M=4, swapped MFMA, register
// heads) + DOUBLE-BUFFERED Acts: stage->A, L1 reads A writes B, L2 reads B
// writes A, L3 reads A. Barriers 8 -> 5, no read-drain/write coupling.
// Epilogue scalars prefetched before L3.
// ---------------------------------------------------------------------------
__global__ __launch_bounds__(128, 2) void mlp_kernel(
    const float* __restrict__ it_g, const float* __restrict__ mask_g,
    const float* __restrict__ au_g, const unsigned short* __restrict__ ctxb,
    const unsigned short* __restrict__ wp,
    const float* __restrict__ b1, const float* __restrict__ b2,
    const float* __restrict__ b3, float* __restrict__ out)
{
    __shared__ __align__(16) unsigned short Acts[2][64 * ASTR];   // 50.2 KB
    __shared__ float wsum[2];

    const int tid = threadIdx.x;
    const int lane = tid & 63;
    const int wv = tid >> 6;
    const int gq = lane >> 4;
    const int cl = lane & 15;
    const long tile = (long)blockIdx.x * 64;
    const int b = (int)(tile >> 12);

    unsigned short* bufA = Acts[0];
    unsigned short* bufB = Acts[1];

    // interleaved n-block ownership (static per j after unroll)
#define NBM(j) ((j) + (((j) >= 2) ? 2 : 0) + (((j) >= 4) ? 2 : 0) + 2 * wv)

    // ---- stage layer-1 input into bufA: ctx cols 0..31, age 32, 0s ----
    {
        int tok = tid >> 1, h = tid & 1;
        unsigned short* row = bufA + tok * ASTR;
        const unsigned short* src = ctxb + (tile + tok) * Dn + h * 16;
        *(short8v*)(row + h * 16)     = *(const short8v*)src;
        *(short8v*)(row + h * 16 + 8) = *(const short8v*)(src + 8);
        short8v z = {0, 0, 0, 0, 0, 0, 0, 0};
        if (h == 0) {
            float itv = it_g[tile + tok];
            float auv = au_g[tile + tok];
            short8v za = z;
            za[0] = (short)f2bf(__logf(fmaf(-auv, itv, itv) + 1e-8f));
            *(short8v*)(row + 32) = za;
        } else {
            *(short8v*)(row + 40) = z;
            *(short8v*)(row + 48) = z;
            *(short8v*)(row + 56) = z;
        }
    }
    __syncthreads();                          // S1: stage visible

    f32x4 acc[6][4];

    auto run_layer = [&](auto NKC, const unsigned short* ap,
                         const unsigned short* wpl, const float* __restrict__ bias) {
        constexpr int nk = NKC.value;
#pragma unroll
        for (int j = 0; j < 6; ++j) {
            f32x4 bb = *(const f32x4*)(bias + NBM(j) * 16 + 4 * gq);
#pragma unroll
            for (int m = 0; m < 4; ++m) acc[j][m] = bb;
        }
#pragma unroll
        for (int ks = 0; ks < nk; ++ks) {
            short8v bfv[4];   // B-operand: acts, lane&15 = token col
#pragma unroll
            for (int m = 0; m < 4; ++m)
                bfv[m] = *(const short8v*)(ap + (m * 16 + cl) * ASTR + ks * 32 + 8 * gq);
            const unsigned short* wk = wpl + (size_t)ks * (12 * 512) + lane * 8;
#pragma unroll
            for (int j = 0; j < 6; ++j) {
                short8v af = *(const short8v*)(wk + NBM(j) * 512);   // A: weights
#pragma unroll
                for (int m = 0; m < 4; ++m)
                    acc[j][m] = __builtin_amdgcn_mfma_f32_16x16x32_bf16(af, bfv[m], acc[j][m], 0, 0, 0);
            }
        }
    };

    auto store_h = [&](unsigned short* dst) {   // relu + packed b64 store
#pragma unroll
        for (int j = 0; j < 6; ++j) {
            int fbase = NBM(j) * 16 + 4 * gq;
#pragma unroll
            for (int m = 0; m < 4; ++m) {
                f32x4 vv = acc[j][m];
#pragma unroll
                for (int r = 0; r < 4; ++r) vv[r] = fmaxf(vv[r], 0.0f);
                uint2 pk;
                pk.x = pack_bf2(vv[0], vv[1]);
                pk.y = pack_bf2(vv[2], vv[3]);
                *(uint2*)(dst + (m * 16 + cl) * ASTR + fbase) = pk;
            }
        }
    };

    run_layer(std::integral_constant<int, 2>{}, bufA, wp, b1);
    store_h(bufB);                            // write B while A reads done in-wave
    __syncthreads();                          // S2: B visible
    run_layer(std::integral_constant<int, 6>{}, bufB, wp + 24 * 512, b2);
    store_h(bufA);                            // write A (L1's A-reads done pre-S2)
    __syncthreads();                          // S3: A visible

    // ---- prefetch epilogue scalars (hide under L3) ----
    float itp[4], aup[4];
#pragma unroll
    for (int m = 0; m < 4; ++m) {
        itp[m] = it_g[tile + m * 16 + cl];
        aup[m] = au_g[tile + m * 16 + cl];
    }
    const int t2 = wv * 32 + (lane & 31);
    float it2 = it_g[tile + t2];
    float au2 = au_g[tile + t2];
    float mk2 = mask_g[tile + t2];

    run_layer(std::integral_constant<int, 6>{}, bufA, wp + 96 * 512, b3);
    // heads stay in f32 registers

    // ---- phase 1: wave-local logsumexp pair per token (comps [32wv,+32)) --
    float lseA[4], lseB[4];
#pragma unroll
    for (int m = 0; m < 4; ++m) {
        float y = __logf(fmaxf(itp[m] * aup[m], 1e-10f));   // resid = it*au

        float m1 = -1e30f;
#pragma unroll
        for (int j = 4; j < 6; ++j)
#pragma unroll
            for (int r = 0; r < 4; ++r) m1 = fmaxf(m1, acc[j][m][r]);
        m1 = fmaxf(m1, __shfl_xor(m1, 16, 64));
        m1 = fmaxf(m1, __shfl_xor(m1, 32, 64));

        float sa = 0.0f, sb = 0.0f;
#pragma unroll
        for (int j = 0; j < 2; ++j) {
#pragma unroll
            for (int r = 0; r < 4; ++r) {
                float loc = acc[j][m][r];
                float lsr = fminf(fmaxf(acc[2 + j][m][r], -5.0f), 3.0f);
                float lg  = acc[4 + j][m][r];
                float zs = (y - loc) * __expf(-lsr);
                float g = -lsr - HALF_LOG2PI - 0.5f * zs * zs;
                sa += __expf(lg - m1);
                sb += __expf(lg - m1 + g);
            }
        }
        sa += __shfl_xor(sa, 16, 64); sa += __shfl_xor(sa, 32, 64);
        sb += __shfl_xor(sb, 16, 64); sb += __shfl_xor(sb, 32, 64);
        lseA[m] = m1 + __logf(sa);
        lseB[m] = m1 + __logf(sb);
    }

    // ---- exchange partials via bufB (free after L2 reads, pre-S3) ----
    float* X = (float*)bufB;
    if (gq == 0) {
#pragma unroll
        for (int m = 0; m < 4; ++m) {
            float2 pr; pr.x = lseA[m]; pr.y = lseB[m];
            *(float2*)(X + (m * 16 + cl) * 4 + wv * 2) = pr;
        }
    }
    __syncthreads();                          // S4: X visible

    // ---- phase 2: combine, mask, reduce. wave wv owns tokens [32wv,+32) ----
    {
        f32x4 pr = *(const f32x4*)(X + t2 * 4);   // a0,b0,a1,b1
        float ma = fmaxf(pr[0], pr[2]);
        float lse_a = ma + __logf(__expf(pr[0] - ma) + __expf(pr[2] - ma));
        float mb = fmaxf(pr[1], pr[3]);
        float lse_b = mb + __logf(__expf(pr[1] - mb) + __expf(pr[3] - mb));

        float y = __logf(fmaxf(it2 * au2, 1e-10f));
        float lp = (lse_b - lse_a - y) * mk2;
        float psum = (lane < 32) ? lp : 0.0f;
#pragma unroll
        for (int mm = 1; mm < 64; mm <<= 1) psum += __shfl_xor(psum, mm, 64);
        if (lane == 0) wsum[wv] = psum;
    }
    __syncthreads();                          // S5: wsum visible
    if (tid == 0) atomicAdd(out + b, wsum[0] + wsum[1]);
#undef NBM
}

// ---------------------------------------------------------------------------
extern "C" void kernel_launch(void* const* d_in, const int* in_sizes, int n_in,
                              void* d_out, int out_size, void* d_ws, size_t ws_size,
                              hipStream_t stream) {
    const float* it_g  = (const float*)d_in[0];
    const float* mask  = (const float*)d_in[1];
    const float* au    = (const float*)d_in[2];
    const float* W     = (const float*)d_in[3];
    const float* v     = (const float*)d_in[4];
    const float* bia   = (const float*)d_in[5];
    const float* cinit = (const float*)d_in[6];
    const float* W1    = (const float*)d_in[7];
    const float* b1    = (const float*)d_in[8];
    const float* W2    = (const float*)d_in[9];
    const float* b2    = (const float*)d_in[10];
    const float* W3    = (const float*)d_in[11];
    const float* b3    = (const float*)d_in[12];
    float* out = (float*)d_out;

    unsigned short* ctxb = (unsigned short*)d_ws;                 // 32 MB
    unsigned short* wp   = ctxb + (size_t)Bn * Sn * Dn;           // 168 KB

    hipMemsetAsync(d_out, 0, (size_t)out_size * sizeof(float), stream);

    pack_weights<<<168, 64, 0, stream>>>(W1, W2, W3, wp);
    recurrence_kernel<<<(Bn * Dn * CH) / 256, 256, 0, stream>>>(
        it_g, W, v, bia, cinit, ctxb);
    mlp_kernel<<<(Bn * Sn) / 64, 128, 0, stream>>>(
        it_g, mask, au, ctxb, wp, b1, b2, b3, out);
}

// Round 17
// 184.600 us; speedup vs baseline: 1.3143x; 1.3143x over previous
//
#include <hip/hip_runtime.h>
#include <hip/hip_bf16.h>
#include <math.h>
#include <type_traits>

#define Bn 128
#define Sn 4096
#define Dn 32
#define Hn 192
#define ASTR 196           // LDS act stride (bf16): proven 0-conflict R5-R16
#define CH 32              // recurrence chunks per chain
#define CHL 128            // steps per chunk
#define BURN 128           // burn-in steps
#define HALF_LOG2PI 0.9189385332046727f

typedef __attribute__((ext_vector_type(8))) short short8v;
typedef __attribute__((ext_vector_type(4))) float f32x4;

__device__ __forceinline__ unsigned short f2bf(float x) {
    return (unsigned short)((__float_as_uint(x) + 0x8000u) >> 16);
}
__device__ __forceinline__ unsigned pack_bf2(float lo, float hi) {
    __hip_bfloat162 h = __float22bfloat162_rn(float2{lo, hi});   // v_cvt_pk_bf16_f32
    return *reinterpret_cast<unsigned*>(&h);
}

// ---------------------------------------------------------------------------
// Pack W1/W2/W3 (fp32 [K][192]) into bf16 MFMA fragment order (proven R2-R16):
// fid = layerbase + kstep*12 + nb; lane elem j: W[k0+8*(lane>>4)+j][nb*16+(lane&15)].
// Used as the A operand (free index = output feature).
// ---------------------------------------------------------------------------
__global__ __launch_bounds__(64) void pack_weights(
    const float* __restrict__ W1, const float* __restrict__ W2,
    const float* __restrict__ W3, unsigned short* __restrict__ wp)
{
    int fid = blockIdx.x, lane = threadIdx.x;
    const float* Wsrc; int Krows, f;
    if (fid < 24)      { Wsrc = W1; Krows = 33;  f = fid; }
    else if (fid < 96) { Wsrc = W2; Krows = 192; f = fid - 24; }
    else               { Wsrc = W3; Krows = 192; f = fid - 96; }
    int kstep = f / 12, nb = f % 12;
    int k0 = kstep * 32 + 8 * (lane >> 4);
    int n  = nb * 16 + (lane & 15);
    short8v v;
#pragma unroll
    for (int j = 0; j < 8; ++j) {
        int k = k0 + j;
        float x = (k < Krows) ? Wsrc[k * Hn + n] : 0.0f;
        v[j] = (short)f2bf(x);
    }
    *(short8v*)(wp + (size_t)fid * 512 + lane * 8) = v;
}

// ---------------------------------------------------------------------------
// Recurrence, chunked (contractive burn-in). Unchanged (proven).
// ---------------------------------------------------------------------------
__global__ __launch_bounds__(256) void recurrence_kernel(
    const float* __restrict__ it_g, const float* __restrict__ W,
    const float* __restrict__ v,    const float* __restrict__ bia,
    const float* __restrict__ cinit, unsigned short* __restrict__ ctx)
{
    const float LOG2E = 1.4426950408889634f;
    int g = blockIdx.x * 256 + threadIdx.x;
    int d = g & 31;
    int bc = g >> 5;
    int b = bc & (Bn - 1);
    int chunk = bc >> 7;

    float w0 = W[d], w3 = W[96 + d];
    float nw1l = -W[32 + d] * LOG2E, nw2l = -W[64 + d] * LOG2E;
    float nvfl = -v[d] * LOG2E,      nvrl = -v[32 + d] * LOG2E;
    float nbfl = -bia[d] * LOG2E,    nbrl = -bia[32 + d] * LOG2E;

    const f32x4* itv = (const f32x4*)(it_g + (size_t)b * Sn);
    unsigned short* cp = ctx + ((size_t)b * Sn) * Dn + d;
    int s_start = chunk * CHL;
    int s_end   = s_start + CHL;
    int sbeg    = (chunk == 0) ? 0 : s_start - BURN;
    if (chunk == 0) cp[0] = f2bf(cinit[d]);

    float c = 0.0f;
    int blk0 = sbeg >> 3, blkN = s_end >> 3;
    f32x4 A0 = itv[blk0 * 2], A1 = itv[blk0 * 2 + 1];
    for (int blk = blk0; blk < blkN; ++blk) {
        f32x4 N0 = A0, N1 = A1;
        if (blk + 1 < blkN) { N0 = itv[blk * 2 + 2]; N1 = itv[blk * 2 + 3]; }
        float feat[8];
#pragma unroll
        for (int j = 0; j < 4; ++j) {
            feat[j]     = __logf(A0[j] + 1e-8f);
            feat[j + 4] = __logf(A1[j] + 1e-8f);
        }
        unsigned short hb[8];
#pragma unroll
        for (int j = 0; j < 8; ++j) {
            float ft = feat[j];
            float u0 = ft * w0, u3 = ft * w3;
            float nxfl = fmaf(ft, nw1l, nbfl);
            float nxrl = fmaf(ft, nw2l, nbrl);
            float sfn = fmaf(nvfl, c, nxfl);
            float ef  = __builtin_amdgcn_exp2f(sfn);
            float f_  = __builtin_amdgcn_rcpf(1.0f + ef);
            float cmu = c - u0;
            float cn  = fmaf(f_, cmu, u0);
            float srn = fmaf(nvrl, cn, nxrl);
            float er  = __builtin_amdgcn_exp2f(srn);
            float r_  = __builtin_amdgcn_rcpf(1.0f + er);
            float h   = fmaf(r_, cn - u3, u3);
            c = cn;
            hb[j] = f2bf(h);
        }
        int s0 = blk * 8;
        if (s0 >= s_start) {
#pragma unroll
            for (int j = 0; j < 8; ++j)
                if (s0 + j + 1 < Sn) cp[(size_t)(s0 + j + 1) * Dn] = hb[j];
        }
        A0 = N0; A1 = N1;
    }
}

// ---------------------------------------------------------------------------
// MLP: 256 threads = 4 waves, 128 tokens/block (M=8). Wave wv owns n-blocks
// {wv, wv+4, wv+8} -> per wave: 42 weight loads (HALF of R15) and complete
// (loc, ls, lg) register triples for comps [16wv,16wv+16) of all 128 tokens.
// Swapped MFMA (A=weights, B=acts), packed b64 stores, register-direct
// 4-way logaddexp epilogue.
// ---------------------------------------------------------------------------
__global__ __launch_bounds__(256, 2) void mlp_kernel(
    const float* __restrict__ it_g, const float* __restrict__ mask_g,
    const float* __restrict__ au_g, const unsigned short* __restrict__ ctxb,
    const unsigned short* __restrict__ wp,
    const float* __restrict__ b1, const float* __restrict__ b2,
    const float* __restrict__ b3, float* __restrict__ out)
{
    __shared__ __align__(16) unsigned short Acts[128 * ASTR];   // 49 KB
    __shared__ float wsum[4];

    const int tid = threadIdx.x;
    const int lane = tid & 63;
    const int wv = tid >> 6;          // 0..3
    const int gq = lane >> 4;
    const int cl = lane & 15;
    const long tile = (long)blockIdx.x * 128;
    const int b = (int)(tile >> 12);

#define NBM(j) (wv + 4 * (j))         // wave's n-blocks: {wv, wv+4, wv+8}

    // ---- stage layer-1 input (token-major): ctx cols 0..31, age 32, 0s ----
    {
        int tok = tid >> 1, h = tid & 1;
        unsigned short* row = Acts + tok * ASTR;
        const unsigned short* src = ctxb + (tile + tok) * Dn + h * 16;
        *(short8v*)(row + h * 16)     = *(const short8v*)src;
        *(short8v*)(row + h * 16 + 8) = *(const short8v*)(src + 8);
        short8v z = {0, 0, 0, 0, 0, 0, 0, 0};
        if (h == 0) {
            float itv = it_g[tile + tok];
            float auv = au_g[tile + tok];
            short8v za = z;
            za[0] = (short)f2bf(__logf(fmaf(-auv, itv, itv) + 1e-8f));
            *(short8v*)(row + 32) = za;
        } else {
            *(short8v*)(row + 40) = z;
            *(short8v*)(row + 48) = z;
            *(short8v*)(row + 56) = z;
        }
    }
    __syncthreads();                          // S1: stage visible

    f32x4 acc[3][8];

    auto run_layer = [&](auto NKC, const unsigned short* wpl,
                         const float* __restrict__ bias) {
        constexpr int nk = NKC.value;
#pragma unroll
        for (int j = 0; j < 3; ++j) {
            f32x4 bb = *(const f32x4*)(bias + NBM(j) * 16 + 4 * gq);
#pragma unroll
            for (int m = 0; m < 8; ++m) acc[j][m] = bb;
        }
#pragma unroll
        for (int ks = 0; ks < nk; ++ks) {
            short8v bfv[8];   // B-operand: acts, lane&15 = token col
#pragma unroll
            for (int m = 0; m < 8; ++m)
                bfv[m] = *(const short8v*)(Acts + (m * 16 + cl) * ASTR + ks * 32 + 8 * gq);
            const unsigned short* wk = wpl + (size_t)ks * (12 * 512) + lane * 8;
#pragma unroll
            for (int j = 0; j < 3; ++j) {
                short8v af = *(const short8v*)(wk + NBM(j) * 512);   // A: weights
#pragma unroll
                for (int m = 0; m < 8; ++m)
                    acc[j][m] = __builtin_amdgcn_mfma_f32_16x16x32_bf16(af, bfv[m], acc[j][m], 0, 0, 0);
            }
        }
    };

    auto store_h = [&]() {   // relu + packed b64 store
#pragma unroll
        for (int j = 0; j < 3; ++j) {
            int fbase = NBM(j) * 16 + 4 * gq;
#pragma unroll
            for (int m = 0; m < 8; ++m) {
                f32x4 vv = acc[j][m];
#pragma unroll
                for (int r = 0; r < 4; ++r) vv[r] = fmaxf(vv[r], 0.0f);
                uint2 pk;
                pk.x = pack_bf2(vv[0], vv[1]);
                pk.y = pack_bf2(vv[2], vv[3]);
                *(uint2*)(Acts + (m * 16 + cl) * ASTR + fbase) = pk;
            }
        }
    };

    run_layer(std::integral_constant<int, 2>{}, wp, b1);
    __syncthreads();                          // S2: drain L1 reads
    store_h();
    __syncthreads();                          // S3: L1 outputs visible
    run_layer(std::integral_constant<int, 6>{}, wp + 24 * 512, b2);
    __syncthreads();                          // S4: drain L2 reads
    store_h();
    __syncthreads();                          // S5: L2 outputs visible

    // ---- prefetch epilogue scalars (hide under L3) ----
    float itp[8], aup[8];
#pragma unroll
    for (int m = 0; m < 8; ++m) {
        itp[m] = it_g[tile + m * 16 + cl];
        aup[m] = au_g[tile + m * 16 + cl];
    }
    float it2 = 0.0f, au2 = 0.0f, mk2 = 0.0f;
    if (tid < 128) {
        it2 = it_g[tile + tid];
        au2 = au_g[tile + tid];
        mk2 = mask_g[tile + tid];
    }

    run_layer(std::integral_constant<int, 6>{}, wp + 96 * 512, b3);
    // heads stay in f32 registers: j=0 -> loc, j=1 -> ls, j=2 -> lg
    // for comps 16*wv + 4*gq + r of token 16*m + cl

    // ---- phase 1: wave-local logsumexp pair per token (16 comps/wave) ----
    float lseA[8], lseB[8];
#pragma unroll
    for (int m = 0; m < 8; ++m) {
        float y = __logf(fmaxf(itp[m] * aup[m], 1e-10f));   // resid = it*au

        float m1 = -1e30f;
#pragma unroll
        for (int r = 0; r < 4; ++r) m1 = fmaxf(m1, acc[2][m][r]);
        m1 = fmaxf(m1, __shfl_xor(m1, 16, 64));
        m1 = fmaxf(m1, __shfl_xor(m1, 32, 64));

        float sa = 0.0f, sb = 0.0f;
#pragma unroll
        for (int r = 0; r < 4; ++r) {
            float loc = acc[0][m][r];
            float lsr = fminf(fmaxf(acc[1][m][r], -5.0f), 3.0f);
            float lg  = acc[2][m][r];
            float zs = (y - loc) * __expf(-lsr);
            float g = -lsr - HALF_LOG2PI - 0.5f * zs * zs;
            sa += __expf(lg - m1);
            sb += __expf(lg - m1 + g);
        }
        sa += __shfl_xor(sa, 16, 64); sa += __shfl_xor(sa, 32, 64);
        sb += __shfl_xor(sb, 16, 64); sb += __shfl_xor(sb, 32, 64);
        lseA[m] = m1 + __logf(sa);
        lseB[m] = m1 + __logf(sb);
    }

    // ---- exchange partials via LDS (Acts free after L3 read-drain) ----
    float* X = (float*)Acts;                  // 128 tokens x 8 f32 = 4 KB
    __syncthreads();                          // S6: drain L3 act reads
    if (gq == 0) {
#pragma unroll
        for (int m = 0; m < 8; ++m) {
            float2 pr; pr.x = lseA[m]; pr.y = lseB[m];
            *(float2*)(X + (m * 16 + cl) * 8 + wv * 2) = pr;
        }
    }
    __syncthreads();                          // S7: X visible

    // ---- phase 2: 4-way combine, mask, reduce (threads 0..127 own tokens)
    {
        float lp = 0.0f;
        if (tid < 128) {
            f32x4 p0 = *(const f32x4*)(X + tid * 8);       // a0,b0,a1,b1
            f32x4 p1 = *(const f32x4*)(X + tid * 8 + 4);   // a2,b2,a3,b3
            float ma = fmaxf(fmaxf(p0[0], p0[2]), fmaxf(p1[0], p1[2]));
            float sa = __expf(p0[0] - ma) + __expf(p0[2] - ma) +
                       __expf(p1[0] - ma) + __expf(p1[2] - ma);
            float mb = fmaxf(fmaxf(p0[1], p0[3]), fmaxf(p1[1], p1[3]));
            float sb = __expf(p0[1] - mb) + __expf(p0[3] - mb) +
                       __expf(p1[1] - mb) + __expf(p1[3] - mb);
            float lse_a = ma + __logf(sa);
            float lse_b = mb + __logf(sb);
            float y = __logf(fmaxf(it2 * au2, 1e-10f));
            lp = (lse_b - lse_a - y) * mk2;
        }
        float psum = lp;
#pragma unroll
        for (int mm = 1; mm < 64; mm <<= 1) psum += __shfl_xor(psum, mm, 64);
        if (lane == 0) wsum[wv] = psum;
    }
    __syncthreads();                          // S8: wsum visible
    if (tid == 0) atomicAdd(out + b, wsum[0] + wsum[1] + wsum[2] + wsum[3]);
#undef NBM
}

// ---------------------------------------------------------------------------
extern "C" void kernel_launch(void* const* d_in, const int* in_sizes, int n_in,
                              void* d_out, int out_size, void* d_ws, size_t ws_size,
                              hipStream_t stream) {
    const float* it_g  = (const float*)d_in[0];
    const float* mask  = (const float*)d_in[1];
    const float* au    = (const float*)d_in[2];
    const float* W     = (const float*)d_in[3];
    const float* v     = (const float*)d_in[4];
    const float* bia   = (const float*)d_in[5];
    const float* cinit = (const float*)d_in[6];
    const float* W1    = (const float*)d_in[7];
    const float* b1    = (const float*)d_in[8];
    const float* W2    = (const float*)d_in[9];
    const float* b2    = (const float*)d_in[10];
    const float* W3    = (const float*)d_in[11];
    const float* b3    = (const float*)d_in[12];
    float* out = (float*)d_out;

    unsigned short* ctxb = (unsigned short*)d_ws;                 // 32 MB
    unsigned short* wp   = ctxb + (size_t)Bn * Sn * Dn;           // 168 KB

    hipMemsetAsync(d_out, 0, (size_t)out_size * sizeof(float), stream);

    pack_weights<<<168, 64, 0, stream>>>(W1, W2, W3, wp);
    recurrence_kernel<<<(Bn * Dn * CH) / 256, 256, 0, stream>>>(
        it_g, W, v, bia, cinit, ctxb);
    mlp_kernel<<<(Bn * Sn) / 128, 256, 0, stream>>>(
        it_g, mask, au, ctxb, wp, b1, b2, b3, out);
}

// Round 18
// 183.668 us; speedup vs baseline: 1.3210x; 1.0051x over previous
//
#include <hip/hip_runtime.h>
#include <hip/hip_bf16.h>
#include <math.h>
#include <type_traits>

#define Bn 128
#define Sn 4096
#define Dn 32
#define Hn 192
#define ASTR 196           // LDS act stride (bf16): proven 0-conflict R5-R17
#define CH 64              // recurrence chunks per chain
#define CHL 64             // steps per chunk
#define BURN 128           // burn-in steps (sbeg clamped at 0)
#define HALF_LOG2PI 0.9189385332046727f

typedef __attribute__((ext_vector_type(8))) short short8v;
typedef __attribute__((ext_vector_type(4))) float f32x4;

__device__ __forceinline__ unsigned short f2bf(float x) {
    return (unsigned short)((__float_as_uint(x) + 0x8000u) >> 16);
}
__device__ __forceinline__ unsigned pack_bf2(float lo, float hi) {
    __hip_bfloat162 h = __float22bfloat162_rn(float2{lo, hi});   // v_cvt_pk_bf16_f32
    return *reinterpret_cast<unsigned*>(&h);
}

// ---------------------------------------------------------------------------
// Pack W1/W2/W3 (fp32 [K][192]) into bf16 MFMA fragment order (proven R2-R17):
// fid = layerbase + kstep*12 + nb; lane elem j: W[k0+8*(lane>>4)+j][nb*16+(lane&15)].
// Used as the A operand (free index = output feature). W1 kstep=1 frags are
// packed but unused (L1 age column handled as rank-1 in the MLP kernel).
// ---------------------------------------------------------------------------
__global__ __launch_bounds__(64) void pack_weights(
    const float* __restrict__ W1, const float* __restrict__ W2,
    const float* __restrict__ W3, unsigned short* __restrict__ wp)
{
    int fid = blockIdx.x, lane = threadIdx.x;
    const float* Wsrc; int Krows, f;
    if (fid < 24)      { Wsrc = W1; Krows = 33;  f = fid; }
    else if (fid < 96) { Wsrc = W2; Krows = 192; f = fid - 24; }
    else               { Wsrc = W3; Krows = 192; f = fid - 96; }
    int kstep = f / 12, nb = f % 12;
    int k0 = kstep * 32 + 8 * (lane >> 4);
    int n  = nb * 16 + (lane & 15);
    short8v v;
#pragma unroll
    for (int j = 0; j < 8; ++j) {
        int k = k0 + j;
        float x = (k < Krows) ? Wsrc[k * Hn + n] : 0.0f;
        v[j] = (short)f2bf(x);
    }
    *(short8v*)(wp + (size_t)fid * 512 + lane * 8) = v;
}

// ---------------------------------------------------------------------------
// Recurrence, chunked (contractive burn-in). CH=64/CHL=64/BURN=128; sbeg
// clamped -> chunks 0,1 are exact, others have >=128-step burn-in.
// ---------------------------------------------------------------------------
__global__ __launch_bounds__(256) void recurrence_kernel(
    const float* __restrict__ it_g, const float* __restrict__ W,
    const float* __restrict__ v,    const float* __restrict__ bia,
    const float* __restrict__ cinit, unsigned short* __restrict__ ctx)
{
    const float LOG2E = 1.4426950408889634f;
    int g = blockIdx.x * 256 + threadIdx.x;
    int d = g & 31;
    int bc = g >> 5;
    int b = bc & (Bn - 1);
    int chunk = bc >> 7;

    float w0 = W[d], w3 = W[96 + d];
    float nw1l = -W[32 + d] * LOG2E, nw2l = -W[64 + d] * LOG2E;
    float nvfl = -v[d] * LOG2E,      nvrl = -v[32 + d] * LOG2E;
    float nbfl = -bia[d] * LOG2E,    nbrl = -bia[32 + d] * LOG2E;

    const f32x4* itv = (const f32x4*)(it_g + (size_t)b * Sn);
    unsigned short* cp = ctx + ((size_t)b * Sn) * Dn + d;
    int s_start = chunk * CHL;
    int s_end   = s_start + CHL;
    int sbeg    = s_start - BURN;
    if (sbeg < 0) sbeg = 0;
    if (chunk == 0) cp[0] = f2bf(cinit[d]);

    float c = 0.0f;
    int blk0 = sbeg >> 3, blkN = s_end >> 3;
    f32x4 A0 = itv[blk0 * 2], A1 = itv[blk0 * 2 + 1];
    for (int blk = blk0; blk < blkN; ++blk) {
        f32x4 N0 = A0, N1 = A1;
        if (blk + 1 < blkN) { N0 = itv[blk * 2 + 2]; N1 = itv[blk * 2 + 3]; }
        float feat[8];
#pragma unroll
        for (int j = 0; j < 4; ++j) {
            feat[j]     = __logf(A0[j] + 1e-8f);
            feat[j + 4] = __logf(A1[j] + 1e-8f);
        }
        unsigned short hb[8];
#pragma unroll
        for (int j = 0; j < 8; ++j) {
            float ft = feat[j];
            float u0 = ft * w0, u3 = ft * w3;
            float nxfl = fmaf(ft, nw1l, nbfl);
            float nxrl = fmaf(ft, nw2l, nbrl);
            float sfn = fmaf(nvfl, c, nxfl);
            float ef  = __builtin_amdgcn_exp2f(sfn);
            float f_  = __builtin_amdgcn_rcpf(1.0f + ef);
            float cmu = c - u0;
            float cn  = fmaf(f_, cmu, u0);
            float srn = fmaf(nvrl, cn, nxrl);
            float er  = __builtin_amdgcn_exp2f(srn);
            float r_  = __builtin_amdgcn_rcpf(1.0f + er);
            float h   = fmaf(r_, cn - u3, u3);
            c = cn;
            hb[j] = f2bf(h);
        }
        int s0 = blk * 8;
        if (s0 >= s_start) {
#pragma unroll
            for (int j = 0; j < 8; ++j)
                if (s0 + j + 1 < Sn) cp[(size_t)(s0 + j + 1) * Dn] = hb[j];
        }
        A0 = N0; A1 = N1;
    }
}

// ---------------------------------------------------------------------------
// MLP: 256 threads = 4 waves, 128 tokens/block (M=8). Wave wv owns n-blocks
// {wv, wv+4, wv+8}. Swapped MFMA (A=weights, B=acts), packed b64 stores,
// register-direct 4-way logaddexp epilogue (R17-proven).
// NEW: L1 age column as rank-1 fp32 update (acc = b1 + W1[32,:]*age_f) ->
// L1 is a single ks=0 MFMA pass; staging writes only ctx cols 0..31.
// ---------------------------------------------------------------------------
__global__ __launch_bounds__(256, 2) void mlp_kernel(
    const float* __restrict__ it_g, const float* __restrict__ mask_g,
    const float* __restrict__ au_g, const unsigned short* __restrict__ ctxb,
    const unsigned short* __restrict__ wp, const float* __restrict__ W1raw,
    const float* __restrict__ b1, const float* __restrict__ b2,
    const float* __restrict__ b3, float* __restrict__ out)
{
    __shared__ __align__(16) unsigned short Acts[128 * ASTR];   // 49 KB
    __shared__ float wsum[4];

    const int tid = threadIdx.x;
    const int lane = tid & 63;
    const int wv = tid >> 6;          // 0..3
    const int gq = lane >> 4;
    const int cl = lane & 15;
    const long tile = (long)blockIdx.x * 128;
    const int b = (int)(tile >> 12);

#define NBM(j) (wv + 4 * (j))         // wave's n-blocks: {wv, wv+4, wv+8}

    // ---- early prefetch of per-token scalars (tokens 16m+cl) ----
    float itp[8], aup[8];
#pragma unroll
    for (int m = 0; m < 8; ++m) {
        itp[m] = it_g[tile + m * 16 + cl];
        aup[m] = au_g[tile + m * 16 + cl];
    }

    // ---- stage layer-1 input (token-major): ctx cols 0..31 only ----
    {
        int tok = tid >> 1, h = tid & 1;
        unsigned short* row = Acts + tok * ASTR;
        const unsigned short* src = ctxb + (tile + tok) * Dn + h * 16;
        *(short8v*)(row + h * 16)     = *(const short8v*)src;
        *(short8v*)(row + h * 16 + 8) = *(const short8v*)(src + 8);
    }
    __syncthreads();                          // S1: stage visible

    // age feature per token (fp32, exact)
    float agef[8];
#pragma unroll
    for (int m = 0; m < 8; ++m)
        agef[m] = __logf(fmaf(-aup[m], itp[m], itp[m]) + 1e-8f);

    f32x4 acc[3][8];

    auto run_layer = [&](auto NKC, const unsigned short* wpl,
                         const float* __restrict__ bias) {
        constexpr int nk = NKC.value;
#pragma unroll
        for (int j = 0; j < 3; ++j) {
            f32x4 bb = *(const f32x4*)(bias + NBM(j) * 16 + 4 * gq);
#pragma unroll
            for (int m = 0; m < 8; ++m) acc[j][m] = bb;
        }
#pragma unroll
        for (int ks = 0; ks < nk; ++ks) {
            short8v bfv[8];   // B-operand: acts, lane&15 = token col
#pragma unroll
            for (int m = 0; m < 8; ++m)
                bfv[m] = *(const short8v*)(Acts + (m * 16 + cl) * ASTR + ks * 32 + 8 * gq);
            const unsigned short* wk = wpl + (size_t)ks * (12 * 512) + lane * 8;
#pragma unroll
            for (int j = 0; j < 3; ++j) {
                short8v af = *(const short8v*)(wk + NBM(j) * 512);   // A: weights
#pragma unroll
                for (int m = 0; m < 8; ++m)
                    acc[j][m] = __builtin_amdgcn_mfma_f32_16x16x32_bf16(af, bfv[m], acc[j][m], 0, 0, 0);
            }
        }
    };

    auto store_h = [&]() {   // relu + packed b64 store
#pragma unroll
        for (int j = 0; j < 3; ++j) {
            int fbase = NBM(j) * 16 + 4 * gq;
#pragma unroll
            for (int m = 0; m < 8; ++m) {
                f32x4 vv = acc[j][m];
#pragma unroll
                for (int r = 0; r < 4; ++r) vv[r] = fmaxf(vv[r], 0.0f);
                uint2 pk;
                pk.x = pack_bf2(vv[0], vv[1]);
                pk.y = pack_bf2(vv[2], vv[3]);
                *(uint2*)(Acts + (m * 16 + cl) * ASTR + fbase) = pk;
            }
        }
    };

    // ---- L1: acc = b1 + W1[32,:] * age_f (rank-1), then single ks=0 ----
    {
#pragma unroll
        for (int j = 0; j < 3; ++j) {
            f32x4 bb  = *(const f32x4*)(b1 + NBM(j) * 16 + 4 * gq);
            f32x4 w32 = *(const f32x4*)(W1raw + 32 * Hn + NBM(j) * 16 + 4 * gq);
#pragma unroll
            for (int m = 0; m < 8; ++m) {
                f32x4 a;
#pragma unroll
                for (int r = 0; r < 4; ++r) a[r] = fmaf(w32[r], agef[m], bb[r]);
                acc[j][m] = a;
            }
        }
        short8v bfv[8];
#pragma unroll
        for (int m = 0; m < 8; ++m)
            bfv[m] = *(const short8v*)(Acts + (m * 16 + cl) * ASTR + 8 * gq);
        const unsigned short* wk = wp + lane * 8;
#pragma unroll
        for (int j = 0; j < 3; ++j) {
            short8v af = *(const short8v*)(wk + NBM(j) * 512);
#pragma unroll
            for (int m = 0; m < 8; ++m)
                acc[j][m] = __builtin_amdgcn_mfma_f32_16x16x32_bf16(af, bfv[m], acc[j][m], 0, 0, 0);
        }
    }
    __syncthreads();                          // S2: drain L1 reads
    store_h();
    __syncthreads();                          // S3: L1 outputs visible
    run_layer(std::integral_constant<int, 6>{}, wp + 24 * 512, b2);
    __syncthreads();                          // S4: drain L2 reads
    store_h();
    __syncthreads();                          // S5: L2 outputs visible

    float it2 = 0.0f, au2 = 0.0f, mk2 = 0.0f;
    if (tid < 128) {
        it2 = it_g[tile + tid];
        au2 = au_g[tile + tid];
        mk2 = mask_g[tile + tid];
    }

    run_layer(std::integral_constant<int, 6>{}, wp + 96 * 512, b3);
    // heads stay in f32 registers: j=0 -> loc, j=1 -> ls, j=2 -> lg
    // for comps 16*wv + 4*gq + r of token 16*m + cl

    // ---- phase 1: wave-local logsumexp pair per token (16 comps/wave) ----
    float lseA[8], lseB[8];
#pragma unroll
    for (int m = 0; m < 8; ++m) {
        float y = __logf(fmaxf(itp[m] * aup[m], 1e-10f));   // resid = it*au

        float m1 = -1e30f;
#pragma unroll
        for (int r = 0; r < 4; ++r) m1 = fmaxf(m1, acc[2][m][r]);
        m1 = fmaxf(m1, __shfl_xor(m1, 16, 64));
        m1 = fmaxf(m1, __shfl_xor(m1, 32, 64));

        float sa = 0.0f, sb = 0.0f;
#pragma unroll
        for (int r = 0; r < 4; ++r) {
            float loc = acc[0][m][r];
            float lsr = fminf(fmaxf(acc[1][m][r], -5.0f), 3.0f);
            float lg  = acc[2][m][r];
            float zs = (y - loc) * __expf(-lsr);
            float g = -lsr - HALF_LOG2PI - 0.5f * zs * zs;
            sa += __expf(lg - m1);
            sb += __expf(lg - m1 + g);
        }
        sa += __shfl_xor(sa, 16, 64); sa += __shfl_xor(sa, 32, 64);
        sb += __shfl_xor(sb, 16, 64); sb += __shfl_xor(sb, 32, 64);
        lseA[m] = m1 + __logf(sa);
        lseB[m] = m1 + __logf(sb);
    }

    // ---- exchange partials via LDS (Acts free after L3 read-drain) ----
    float* X = (float*)Acts;                  // 128 tokens x 8 f32 = 4 KB
    __syncthreads();                          // S6: drain L3 act reads
    if (gq == 0) {
#pragma unroll
        for (int m = 0; m < 8; ++m) {
            float2 pr; pr.x = lseA[m]; pr.y = lseB[m];
            *(float2*)(X + (m * 16 + cl) * 8 + wv * 2) = pr;
        }
    }
    __syncthreads();                          // S7: X visible

    // ---- phase 2: 4-way combine, mask, reduce (threads 0..127 own tokens)
    {
        float lp = 0.0f;
        if (tid < 128) {
            f32x4 p0 = *(const f32x4*)(X + tid * 8);       // a0,b0,a1,b1
            f32x4 p1 = *(const f32x4*)(X + tid * 8 + 4);   // a2,b2,a3,b3
            float ma = fmaxf(fmaxf(p0[0], p0[2]), fmaxf(p1[0], p1[2]));
            float sa = __expf(p0[0] - ma) + __expf(p0[2] - ma) +
                       __expf(p1[0] - ma) + __expf(p1[2] - ma);
            float mb = fmaxf(fmaxf(p0[1], p0[3]), fmaxf(p1[1], p1[3]));
            float sb = __expf(p0[1] - mb) + __expf(p0[3] - mb) +
                       __expf(p1[1] - mb) + __expf(p1[3] - mb);
            float lse_a = ma + __logf(sa);
            float lse_b = mb + __logf(sb);
            float y = __logf(fmaxf(it2 * au2, 1e-10f));
            lp = (lse_b - lse_a - y) * mk2;
        }
        float psum = lp;
#pragma unroll
        for (int mm = 1; mm < 64; mm <<= 1) psum += __shfl_xor(psum, mm, 64);
        if (lane == 0) wsum[wv] = psum;
    }
    __syncthreads();                          // S8: wsum visible
    if (tid == 0) atomicAdd(out + b, wsum[0] + wsum[1] + wsum[2] + wsum[3]);
#undef NBM
}

// ---------------------------------------------------------------------------
extern "C" void kernel_launch(void* const* d_in, const int* in_sizes, int n_in,
                              void* d_out, int out_size, void* d_ws, size_t ws_size,
                              hipStream_t stream) {
    const float* it_g  = (const float*)d_in[0];
    const float* mask  = (const float*)d_in[1];
    const float* au    = (const float*)d_in[2];
    const float* W     = (const float*)d_in[3];
    const float* v     = (const float*)d_in[4];
    const float* bia   = (const float*)d_in[5];
    const float* cinit = (const float*)d_in[6];
    const float* W1    = (const float*)d_in[7];
    const float* b1    = (const float*)d_in[8];
    const float* W2    = (const float*)d_in[9];
    const float* b2    = (const float*)d_in[10];
    const float* W3    = (const float*)d_in[11];
    const float* b3    = (const float*)d_in[12];
    float* out = (float*)d_out;

    unsigned short* ctxb = (unsigned short*)d_ws;                 // 32 MB
    unsigned short* wp   = ctxb + (size_t)Bn * Sn * Dn;           // 168 KB

    hipMemsetAsync(d_out, 0, (size_t)out_size * sizeof(float), stream);

    pack_weights<<<168, 64, 0, stream>>>(W1, W2, W3, wp);
    recurrence_kernel<<<(Bn * Dn * CH) / 256, 256, 0, stream>>>(
        it_g, W, v, bia, cinit, ctxb);
    mlp_kernel<<<(Bn * Sn) / 128, 256, 0, stream>>>(
        it_g, mask, au, ctxb, wp, W1, b1, b2, b3, out);
}